// Round 1
// 705.768 us; speedup vs baseline: 1.0402x; 1.0402x over previous
//
#include <hip/hip_runtime.h>
#include <cmath>

#define B_N 2048
#define L_N 200
#define D_N 256
// PAD = float(-2^32+1) rounds to -2^32 in fp32; reference divides by 16 after masking.
#define PAD16 (-268435456.0f)

// M = W_query @ W_key^T  [256x256]
__global__ __launch_bounds__(256) void k_mat(const float* __restrict__ Wq,
                                             const float* __restrict__ Wk,
                                             float* __restrict__ M) {
  __shared__ float wq[D_N];
  const int d = blockIdx.x, f = threadIdx.x;
  wq[f] = Wq[d * D_N + f];
  __syncthreads();
  const float4* wk4 = (const float4*)(Wk + (size_t)f * D_N);
  const float4* wq4 = (const float4*)wq;
  float acc = 0.f;
#pragma unroll 16
  for (int e = 0; e < D_N / 4; ++e) {
    float4 a = wq4[e], b = wk4[e];
    acc += a.x * b.x + a.y * b.y + a.z * b.z + a.w * b.w;
  }
  M[d * D_N + f] = acc;
}

// Y[b,f] = sum_d X[b,d] * W[d,f]
// 4 batch rows per block (512 blocks -> 2 blocks/CU, 2 waves/SIMD: 2x occupancy
// vs the previous 8-row/256-block version which had 1 wave/SIMD and no latency
// hiding). LDS reads vectorized to ds_read_b128 (4 floats of X per read).
__global__ __launch_bounds__(256) void k_rowgemm(const float* __restrict__ X,
                                                 const float* __restrict__ W,
                                                 float* __restrict__ Y) {
  __shared__ float xs[4 * D_N];
  const int f = threadIdx.x;
  const int b0 = blockIdx.x * 4;
  // stage 4 rows (1024 floats) with one float4 per thread
  ((float4*)xs)[f] = ((const float4*)(X + (size_t)b0 * D_N))[f];
  __syncthreads();
  float acc[4] = {0.f, 0.f, 0.f, 0.f};
  const float4* xs4 = (const float4*)xs;  // [4][64]
#pragma unroll 4
  for (int d4 = 0; d4 < D_N / 4; ++d4) {
    const float* wc = W + (size_t)(d4 * 4) * D_N + f;
    const float w0 = wc[0];
    const float w1 = wc[D_N];
    const float w2 = wc[2 * D_N];
    const float w3 = wc[3 * D_N];
#pragma unroll
    for (int j = 0; j < 4; ++j) {
      const float4 x = xs4[j * 64 + d4];
      acc[j] += x.x * w0 + x.y * w1 + x.z * w2 + x.w * w3;
    }
  }
#pragma unroll
  for (int j = 0; j < 4; ++j) Y[(size_t)(b0 + j) * D_N + f] = acc[j];
}

__device__ __forceinline__ float wave_dot(const float4 kv, const float4 qk) {
  float p = kv.x * qk.x + kv.y * qk.y + kv.z * qk.z + kv.w * qk.w;
#pragma unroll
  for (int off = 1; off < 64; off <<= 1) p += __shfl_xor(p, off);
  return p;
}

// One block per batch. Single pass over valid k rows with per-wave online
// softmax, 2 rows per iteration for ILP (two independent shfl-reduce trees).
// Memory-optimal: each valid K row is loaded exactly once (coalesced dwordx4)
// and used for both the dot product and the weighted sum from registers.
__global__ __launch_bounds__(256) void k_attn(const float* __restrict__ QK,
                                              const float* __restrict__ K,
                                              const int* __restrict__ keys_length,
                                              const float* __restrict__ bias,
                                              float* __restrict__ S) {
  const int b = blockIdx.x;
  const int tid = threadIdx.x;
  const int lane = tid & 63;
  const int wid = tid >> 6;
  const int kl = keys_length[b];
  const float bias256 = bias[0] * (float)D_N;
  const float4 qk4 = ((const float4*)(QK + (size_t)b * D_N))[lane];
  const float* kb = K + (size_t)b * L_N * D_N;

  float m = -INFINITY, Z = 0.f;
  float4 acc = make_float4(0.f, 0.f, 0.f, 0.f);
  // kl==0: all rows masked -> uniform softmax over all 200 (reference semantics)
  const int Lcap = (kl > 0) ? kl : L_N;

  int l = wid;
  // paired iterations: rows l and l+4 — independent load+reduce chains
  for (; l + 4 < Lcap; l += 8) {
    const float4 kv0 = ((const float4*)(kb + (size_t)l * D_N))[lane];
    const float4 kv1 = ((const float4*)(kb + (size_t)(l + 4) * D_N))[lane];
    const float p0 = wave_dot(kv0, qk4);
    const float p1 = wave_dot(kv1, qk4);
    const float s0 = (l < kl)
        ? 0.0625f * __builtin_amdgcn_rcpf(1.f + __expf(-(p0 + bias256)))
        : PAD16;
    const float s1 = (l + 4 < kl)
        ? 0.0625f * __builtin_amdgcn_rcpf(1.f + __expf(-(p1 + bias256)))
        : PAD16;
    const float mn = fmaxf(fmaxf(m, s0), s1);  // v_max3_f32
    const float al = __expf(m - mn);           // first iter: exp(-inf)=0
    const float e0 = __expf(s0 - mn);
    const float e1 = __expf(s1 - mn);
    acc.x = acc.x * al + e0 * kv0.x + e1 * kv1.x;
    acc.y = acc.y * al + e0 * kv0.y + e1 * kv1.y;
    acc.z = acc.z * al + e0 * kv0.z + e1 * kv1.z;
    acc.w = acc.w * al + e0 * kv0.w + e1 * kv1.w;
    Z = Z * al + e0 + e1;
    m = mn;
  }
  if (l < Lcap) {  // remainder row
    const float4 kv0 = ((const float4*)(kb + (size_t)l * D_N))[lane];
    const float p0 = wave_dot(kv0, qk4);
    const float s0 = (l < kl)
        ? 0.0625f * __builtin_amdgcn_rcpf(1.f + __expf(-(p0 + bias256)))
        : PAD16;
    const float mn = fmaxf(m, s0);
    const float al = __expf(m - mn);
    const float e0 = __expf(s0 - mn);
    acc.x = acc.x * al + e0 * kv0.x;
    acc.y = acc.y * al + e0 * kv0.y;
    acc.z = acc.z * al + e0 * kv0.z;
    acc.w = acc.w * al + e0 * kv0.w;
    Z = Z * al + e0;
    m = mn;
  }

  // merge the 4 per-wave states
  __shared__ float mw[4], zw[4];
  __shared__ float accw[4][D_N];
  if (lane == 0) { mw[wid] = m; zw[wid] = Z; }
  ((float4*)(accw[wid]))[lane] = acc;
  __syncthreads();
  const float M4 = fmaxf(fmaxf(mw[0], mw[1]), fmaxf(mw[2], mw[3]));
  float Zt = 0.f, s = 0.f;
#pragma unroll
  for (int w = 0; w < 4; ++w) {
    const float beta = __expf(mw[w] - M4);  // empty wave: exp(-inf)=0
    Zt += zw[w] * beta;
    s += accw[w][tid] * beta;
  }
  S[(size_t)b * D_N + tid] = s * __builtin_amdgcn_rcpf(Zt);
}

extern "C" void kernel_launch(void* const* d_in, const int* in_sizes, int n_in,
                              void* d_out, int out_size, void* d_ws, size_t ws_size,
                              hipStream_t stream) {
  const float* q = (const float*)d_in[0];
  const float* k = (const float*)d_in[1];
  // d_in[2] = v : unused by the reference (is_keys_diff=True path)
  const int* keys_length = (const int*)d_in[3];
  const float* Wq = (const float*)d_in[4];
  const float* Wk = (const float*)d_in[5];
  const float* Wv = (const float*)d_in[6];
  const float* bias = (const float*)d_in[7];
  float* out = (float*)d_out;

  float* M = (float*)d_ws;         // 256*256
  float* QK = M + D_N * D_N;       // 2048*256
  float* S = QK + B_N * D_N;       // 2048*256  (total ws: ~4.25 MB)

  k_mat<<<D_N, D_N, 0, stream>>>(Wq, Wk, M);
  k_rowgemm<<<B_N / 4, D_N, 0, stream>>>(q, M, QK);
  k_attn<<<B_N, D_N, 0, stream>>>(QK, k, keys_length, bias, S);
  k_rowgemm<<<B_N / 4, D_N, 0, stream>>>(S, Wv, out);
}